// Round 15
// baseline (253.072 us; speedup 1.0000x reference)
//
#include <hip/hip_runtime.h>
#include <stdint.h>

// Problem constants (B,S,H)=(2,2048,2048), NH=16, NKV=2, HD=128, theta=1e6
#define Bsz  2
#define Ssz  2048
#define Hsz  2048
#define NHh  16
#define NKVh 2
#define HDd  128
#define NQKV 2560   // H + 2*KV = 2048 + 512

typedef __attribute__((ext_vector_type(8))) short bfrag;  // 8 x bf16 (4 VGPRs)
typedef __attribute__((ext_vector_type(4))) float facc;   // MFMA f32 accum

#define AS1 __attribute__((address_space(1)))
#define AS3 __attribute__((address_space(3)))

__device__ __forceinline__ ushort f2bf(float x){
  union { float f; uint32_t u; } v; v.f = x;
  return (ushort)((v.u + 0x7fffu + ((v.u >> 16) & 1u)) >> 16);
}
__device__ __forceinline__ float bf2f(ushort x){
  union { uint32_t u; float f; } v; v.u = ((uint32_t)x) << 16; return v.f;
}
__device__ __forceinline__ uint32_t cvt_pk_bf16(float a, float b){
  uint32_t r;
  asm("v_cvt_pk_bf16_f32 %0, %1, %2" : "=v"(r) : "v"(a), "v"(b));
  return r;   // lo16 = bf16(a), hi16 = bf16(b), RNE
}

// ---- fp32 -> bf16 bulk convert (X) ----
__global__ void k_convert(const float* __restrict__ in, ushort* __restrict__ out){
  const size_t i = ((size_t)blockIdx.x * 256 + threadIdx.x) * 4;
  const float4 v = *(const float4*)(in + i);
  ushort4 o;
  o.x = f2bf(v.x); o.y = f2bf(v.y); o.z = f2bf(v.z); o.w = f2bf(v.w);
  *(ushort4*)(out + i) = o;
}

// ---- transpose-convert: in (2048 x N) f32 row-major -> out bf16 rows (rowoff+n), ld 2048 ----
__global__ void k_transpose(const float* __restrict__ in, ushort* __restrict__ out,
                            int N, int rowoff){
  __shared__ float t[32][33];
  const int k0 = blockIdx.x * 32, n0 = blockIdx.y * 32;
  const int tx = threadIdx.x, ty = threadIdx.y; // 32 x 8
#pragma unroll
  for (int i = 0; i < 4; ++i)
    t[ty + i*8][tx] = in[(size_t)(k0 + ty + i*8) * N + n0 + tx];
  __syncthreads();
#pragma unroll
  for (int i = 0; i < 4; ++i)
    out[(size_t)(rowoff + n0 + ty + i*8) * 2048 + k0 + tx] = f2bf(t[tx][ty + i*8]);
}

// ---- RoPE cos/sin table + bias concat (merged) ----
__global__ void k_prep(const int* __restrict__ pos, float* __restrict__ cosb,
                       float* __restrict__ sinb, const float* __restrict__ bq,
                       const float* __restrict__ bk, const float* __restrict__ bv,
                       float* __restrict__ bqkv){
  const int s = blockIdx.x, j = threadIdx.x; // 64 threads
  const float p = (float)pos[s];
  const float fr = expf(-(float)j * (13.815510557964274f / 64.f)); // 1/theta^(j/64)
  const float t = p * fr;
  cosb[s*64 + j] = cosf(t);
  sinb[s*64 + j] = sinf(t);
  const int idx = s*64 + j;
  if (idx < 2560)
    bqkv[idx] = idx < 2048 ? bq[idx] : (idx < 2304 ? bk[idx-2048] : bv[idx-2304]);
}

// ---- 2-phase prefetch bf16 GEMM: C[M,N] = A[M,K] * Bt[N,K]^T (+bias) ----
// If vtout != nullptr, blocks with n0 >= 2304 (V columns of the QKV GEMM) write
// output TRANSPOSED into vt (b,kv,d,s) as packed ushort4 (replaces k_vt).
template<bool HAS_BIAS, bool OUT_BF16>
__global__ __launch_bounds__(256, 3) void k_gemm(const ushort* __restrict__ A,
                                                 const ushort* __restrict__ Bt,
                                                 const float* __restrict__ bias,
                                                 void* __restrict__ Cout,
                                                 ushort* __restrict__ vtout,
                                                 int N, int K){
  __shared__ ushort As[2][128*32];
  __shared__ ushort Bs[2][128*32];
  const int m0 = blockIdx.x * 128;
  const int n0 = blockIdx.y * 128;
  const int tid = threadIdx.x;
  const int wave = tid >> 6, lane = tid & 63;
  const int wm = wave >> 1, wn = wave & 1;
  const int lrow = lane >> 4, lcol = lane & 15;
  facc acc[4][4] = {};

  auto stage = [&](int t, int buf){
    const int k0 = t * 32;
#pragma unroll
    for (int i = 0; i < 2; ++i){
      const int chunk = wave*2 + i;            // 0..7
      const int slot  = chunk*64 + lane;       // 0..511
      const int row   = slot >> 2, col8 = (slot & 3) * 8;
      const ushort* ga = A  + (size_t)(m0 + row) * K + k0 + col8;
      const ushort* gb = Bt + (size_t)(n0 + row) * K + k0 + col8;
      __builtin_amdgcn_global_load_lds((const AS1 void*)ga,
          (AS3 void*)(&As[buf][chunk*512]), 16, 0, 0);
      __builtin_amdgcn_global_load_lds((const AS1 void*)gb,
          (AS3 void*)(&Bs[buf][chunk*512]), 16, 0, 0);
    }
  };

  stage(0, 0);
  __syncthreads();
  const int nT = K >> 5;
  for (int t = 0; t < nT; ++t){
    const int buf = t & 1;
    if (t + 1 < nT) stage(t + 1, buf ^ 1);   // prefetch next tile (other buffer)
    bfrag af[4], bf[4];
#pragma unroll
    for (int mi = 0; mi < 4; ++mi)
      af[mi] = *(const bfrag*)(&As[buf][(wm*64 + mi*16 + lcol)*32 + lrow*8]);
#pragma unroll
    for (int ni = 0; ni < 4; ++ni)
      bf[ni] = *(const bfrag*)(&Bs[buf][(wn*64 + ni*16 + lcol)*32 + lrow*8]);
#pragma unroll
    for (int mi = 0; mi < 4; ++mi)
#pragma unroll
      for (int ni = 0; ni < 4; ++ni)
        acc[mi][ni] = __builtin_amdgcn_mfma_f32_16x16x32_bf16(af[mi], bf[ni], acc[mi][ni], 0, 0, 0);
    __syncthreads();                         // drains prefetch loads + LDS reads
  }

  if (vtout != nullptr && n0 >= 2304){       // V columns -> vt (b,kv,d,s), transposed
#pragma unroll
    for (int mi = 0; mi < 4; ++mi){
#pragma unroll
      for (int ni = 0; ni < 4; ++ni){
        const int col = n0 + wn*64 + ni*16 + lcol;   // 2304..2559
        const float bsv = HAS_BIAS ? bias[col] : 0.f;
        const int cv = col - 2304;
        const int kv = cv >> 7, d = cv & 127;
        const int row0 = m0 + wm*64 + mi*16 + lrow*4;
        const int bb = row0 >> 11, s0 = row0 & 2047;
        ushort4 w;
        w.x = f2bf(acc[mi][ni][0] + bsv);
        w.y = f2bf(acc[mi][ni][1] + bsv);
        w.z = f2bf(acc[mi][ni][2] + bsv);
        w.w = f2bf(acc[mi][ni][3] + bsv);
        *(ushort4*)(vtout + ((size_t)((bb*NKVh + kv)*HDd + d))*Ssz + s0) = w;
      }
    }
    return;
  }
#pragma unroll
  for (int mi = 0; mi < 4; ++mi){
#pragma unroll
    for (int ni = 0; ni < 4; ++ni){
      const int col = n0 + wn*64 + ni*16 + lcol;
      const float bsv = HAS_BIAS ? bias[col] : 0.f;
#pragma unroll
      for (int r = 0; r < 4; ++r){
        const size_t row = (size_t)m0 + wm*64 + mi*16 + lrow*4 + r;
        const float v = acc[mi][ni][r] + bsv;
        if (OUT_BF16) ((ushort*)Cout)[row * N + col] = f2bf(v);
        else          ((float*) Cout)[row * N + col] = v;
      }
    }
  }
}

// ---- in-place RoPE on q (cols 0..2047) and k (cols 2048..2303) of qkv ----
__global__ void k_rope(ushort* __restrict__ qkv, const float* __restrict__ cosb,
                       const float* __restrict__ sinb){
  const int s = blockIdx.x, b = blockIdx.y;
  ushort* rp = qkv + ((size_t)(b*Ssz + s)) * NQKV;
  const float* cb = cosb + s*64;
  const float* sb = sinb + s*64;
  for (int i = threadIdx.x; i < 18*64; i += 256){  // 16 q-heads + 2 kv-heads
    const int hh = i >> 6, d = i & 63;
    ushort* p = rp + hh*128 + d;
    const float x1 = bf2f(p[0]), x2 = bf2f(p[64]);
    const float c = cb[d], sn = sb[d];
    p[0]  = f2bf(x1*c  - x2*sn);
    p[64] = f2bf(x1*sn + x2*c);
  }
}

// ---- causal GQA flash attention, round 15: 1-q-tile/block + K/V DOUBLE-BUFFER ----
// 1024 blocks x 4 waves, qt = b ? 31-x : x (co-resident pair {i, i+512} differs only
// in b -> each CU's pair totals 33 steps; queued blocks backfill dynamically).
// K/V staged via global_load_lds DMA (zero staging VGPRs, spill-proof), DOUBLE-
// buffered: DMA(t+1)->buf^1 issued BEFORE step(t) reads buf, ONE barrier per
// iteration whose vmcnt(0) drain has a full step of compute slack (round-7 GEMM
// pattern). LDS 72KB = 2x16K K + 2x16K V + 8K P -> 2 blocks/CU.
__global__ __launch_bounds__(256, 2) void k_attn(const ushort* __restrict__ qkv,
                                                 const ushort* __restrict__ vt,
                                                 ushort* __restrict__ out){
  __shared__ __attribute__((aligned(16))) char klds2[2*16384];  // K dbuf 64 x 256B, swizzled
  __shared__ __attribute__((aligned(16))) char vlds2[2*16384];  // V^T dbuf 128 x 128B, swizzled
  __shared__ __attribute__((aligned(16))) char plds[4*2048];    // per-wave P 16 x 128B, swizzled
  const int bx = blockIdx.x, h = blockIdx.y, b = blockIdx.z;
  const int qt = b ? (31 - bx) : bx;              // complementary co-residency swizzle
  const int kvh = h >> 3;                         // rep = NH/NKV = 8
  const int tid = threadIdx.x, wave = tid >> 6, lane = tid & 63;
  const int lrow = lane >> 4, lcol = lane & 15;

  bfrag qf[4];
  {
    const ushort* qp = qkv + ((size_t)b*Ssz + qt*64 + wave*16 + lcol)*NQKV + h*HDd + lrow*8;
#pragma unroll
    for (int kk = 0; kk < 4; ++kk) qf[kk] = *(const bfrag*)(qp + kk*32);
  }
  facc acc[8] = {};
  float m = -1e30f, l = 0.f;               // per-lane softmax state for q = lcol (log2 domain)

  const ushort* kb = qkv + (size_t)b*Ssz*NQKV + Hsz + kvh*HDd;
  const ushort* vb = vt + ((size_t)(b*NKVh + kvh))*HDd*Ssz;
  char* pw = plds + wave*2048;
  const int qloc = wave*16 + lcol;         // this lane's q row within the 64-row q-tile

  // K tile (64 x 256B) + V tile (128 x 128B) -> LDS buffer via DMA, source
  // pre-swizzled: LDS slot (row, c) holds X[row][c ^ ((row&7)<<4)].
  auto issueKV = [&](int t, char* kdst, char* vdst){
    const ushort* kt = kb + (size_t)t*64*NQKV;
#pragma unroll
    for (int i = 0; i < 4; ++i){
      const int g = i*256 + tid;
      const int row = g >> 4, c = (g & 15) * 16;
      const char* src = (const char*)(kt + (size_t)row*NQKV) + (c ^ ((row & 7) << 4));
      __builtin_amdgcn_global_load_lds((const AS1 void*)src,
          (AS3 void*)(kdst + i*4096 + wave*1024), 16, 0, 0);
    }
#pragma unroll
    for (int i = 0; i < 4; ++i){
      const int g = i*256 + tid;
      const int d = g >> 3, c = (g & 7) * 16;
      const char* src = (const char*)(vb + (size_t)d*Ssz + t*64) + (c ^ ((d & 7) << 4));
      __builtin_amdgcn_global_load_lds((const AS1 void*)src,
          (AS3 void*)(vdst + i*4096 + wave*1024), 16, 0, 0);
    }
  };

  auto step = [&](int t, const char* kcur, const char* vcur){
    facc sc[4] = {};
#pragma unroll
    for (int kk = 0; kk < 4; ++kk){        // S^T = K·Q^T: 16 MFMA, swizzled K reads
#pragma unroll
      for (int nt = 0; nt < 4; ++nt){
        const bfrag kf = *(const bfrag*)(kcur + (nt*16 + lcol)*256 +
                                         ((kk*64 + lrow*16) ^ ((lcol & 7) << 4)));
        sc[nt] = __builtin_amdgcn_mfma_f32_16x16x32_bf16(kf, qf[kk], sc[nt], 0, 0, 0);
      }
    }
    const bool diag = (t == qt);
    float tm = -1e30f;
#pragma unroll
    for (int nt = 0; nt < 4; ++nt){        // scale+mask in place, running max
#pragma unroll
      for (int r = 0; r < 4; ++r){
        float sv = sc[nt][r] * 0.12752585778442352f;   // log2(e)/sqrt(128)
        if (diag && (nt*16 + lrow*4 + r) > qloc) sv = -1e30f;
        sc[nt][r] = sv;
        tm = fmaxf(tm, sv);
      }
    }
    tm = fmaxf(tm, __shfl_xor(tm, 16));    // reduce over the 4 k-groups
    tm = fmaxf(tm, __shfl_xor(tm, 32));
    float mn = m, corr = 1.f;
    if (!__all(tm <= m + 11.5f)){          // defer-max: skip rescale when bounded
      mn = fmaxf(m, tm);
      corr = exp2f(m - mn);
#pragma unroll
      for (int r = 0; r < 4; ++r){
        const float ct = __shfl(corr, lrow*4 + r);
#pragma unroll
        for (int dt = 0; dt < 8; ++dt) acc[dt][r] *= ct;
      }
      m = mn;
    }
    float rs = 0.f;
#pragma unroll
    for (int nt = 0; nt < 4; ++nt){        // exp, sum, cvt_pk pack, P -> LDS 8B
      const float e0 = exp2f(sc[nt][0] - mn);
      const float e1 = exp2f(sc[nt][1] - mn);
      const float e2 = exp2f(sc[nt][2] - mn);
      const float e3 = exp2f(sc[nt][3] - mn);
      rs += (e0 + e1) + (e2 + e3);
      uint2 w;
      w.x = cvt_pk_bf16(e0, e1);
      w.y = cvt_pk_bf16(e2, e3);
      *(uint2*)(pw + lcol*128 + ((nt*32 + lrow*8) ^ ((lcol & 7) << 4))) = w;
    }
    rs += __shfl_xor(rs, 16);
    rs += __shfl_xor(rs, 32);
    l = l*corr + rs;
    asm volatile("s_waitcnt lgkmcnt(0)" ::: "memory");
#pragma unroll
    for (int kk2 = 0; kk2 < 2; ++kk2){     // PV: 16 MFMA, swizzled P/V reads
      const bfrag pa = *(const bfrag*)(pw + lcol*128 +
                                       ((kk2*64 + lrow*16) ^ ((lcol & 7) << 4)));
#pragma unroll
      for (int dt = 0; dt < 8; ++dt){
        const int vrow = dt*16 + lcol;
        const bfrag vf = *(const bfrag*)(vcur + vrow*128 +
                                         ((kk2*64 + lrow*16) ^ ((vrow & 7) << 4)));
        acc[dt] = __builtin_amdgcn_mfma_f32_16x16x32_bf16(pa, vf, acc[dt], 0, 0, 0);
      }
    }
  };

  issueKV(0, klds2, vlds2);
  __syncthreads();                         // drain tile-0 DMA
  int cur = 0;
  for (int t = 0; t <= qt; ++t){
    if (t < qt)                            // prefetch next tile into other buffer
      issueKV(t + 1, klds2 + (cur ^ 1)*16384, vlds2 + (cur ^ 1)*16384);
    step(t, klds2 + cur*16384, vlds2 + cur*16384);
    __syncthreads();                       // reads done + DMA(t+1) drained (full
    cur ^= 1;                              //  step of compute slack before this)
  }

  float lt[4];
#pragma unroll
  for (int r = 0; r < 4; ++r) lt[r] = __shfl(l, lrow*4 + r);
#pragma unroll
  for (int r = 0; r < 4; ++r){
    const float inv = 1.f / lt[r];
    ushort* op = out + ((size_t)b*Ssz + qt*64 + wave*16 + lrow*4 + r)*Hsz + h*HDd;
#pragma unroll
    for (int dt = 0; dt < 8; dt += 2){
      const uint32_t u = cvt_pk_bf16(acc[dt][r] * inv, acc[dt+1][r] * inv);
      op[dt*16 + lcol]     = (ushort)(u & 0xffffu);
      op[(dt+1)*16 + lcol] = (ushort)(u >> 16);
    }
  }
}

extern "C" void kernel_launch(void* const* d_in, const int* in_sizes, int n_in,
                              void* d_out, int out_size, void* d_ws, size_t ws_size,
                              hipStream_t stream){
  (void)in_sizes; (void)n_in; (void)out_size;
  const float* hs  = (const float*)d_in[0];
  // d_in[1] = attention_mask: exactly causal 0/-1e9, applied analytically in k_attn
  const int*   pos = (const int*)  d_in[2];
  const float* Wq  = (const float*)d_in[3];
  const float* bq  = (const float*)d_in[4];
  const float* Wk  = (const float*)d_in[5];
  const float* bk  = (const float*)d_in[6];
  const float* Wv  = (const float*)d_in[7];
  const float* bv  = (const float*)d_in[8];
  const float* Wo  = (const float*)d_in[9];

  if (ws_size < 59779072) return;  // need ~57 MB scratch

  char* ws = (char*)d_ws;
  ushort* Xbf   = (ushort*)(ws + 0);          // 16,777,216 B; reused as attn output
  ushort* WqkvT = (ushort*)(ws + 16777216);   // 10,485,760 B (2560 x 2048 bf16)
  ushort* WoT   = (ushort*)(ws + 27262976);   //  8,388,608 B
  float*  bqkv  = (float*) (ws + 35651584);   //     10,240 B
  float*  cosb  = (float*) (ws + 35661824);   //    524,288 B
  float*  sinb  = (float*) (ws + 36186112);   //    524,288 B
  ushort* qkv   = (ushort*)(ws + 36710400);   // 20,971,520 B (4096 x 2560 bf16)
  ushort* vt    = (ushort*)(ws + 57681920);   //  2,097,152 B
  ushort* attn  = Xbf;

  k_convert  <<<8192, 256, 0, stream>>>(hs, Xbf);
  k_transpose<<<dim3(64,64), dim3(32,8), 0, stream>>>(Wq, WqkvT, 2048, 0);
  k_transpose<<<dim3(64, 8), dim3(32,8), 0, stream>>>(Wk, WqkvT, 256, 2048);
  k_transpose<<<dim3(64, 8), dim3(32,8), 0, stream>>>(Wv, WqkvT, 256, 2304);
  k_transpose<<<dim3(64,64), dim3(32,8), 0, stream>>>(Wo, WoT, 2048, 0);
  k_prep     <<<2048, 64, 0, stream>>>(pos, cosb, sinb, bq, bk, bv, bqkv);
  k_gemm<true,  true ><<<dim3(32,20), 256, 0, stream>>>(Xbf, WqkvT, bqkv, qkv, vt, 2560, 2048);
  k_rope     <<<dim3(2048,2), 256, 0, stream>>>(qkv, cosb, sinb);
  k_attn     <<<dim3(32,16,2), 256, 0, stream>>>(qkv, vt, attn);
  k_gemm<false, false><<<dim3(32,16), 256, 0, stream>>>(attn, WoT, nullptr, d_out, nullptr, 2048, 2048);
}

// Round 16
// 225.726 us; speedup vs baseline: 1.1211x; 1.1211x over previous
//
#include <hip/hip_runtime.h>
#include <stdint.h>

// Problem constants (B,S,H)=(2,2048,2048), NH=16, NKV=2, HD=128, theta=1e6
#define Bsz  2
#define Ssz  2048
#define Hsz  2048
#define NHh  16
#define NKVh 2
#define HDd  128
#define NQKV 2560   // H + 2*KV = 2048 + 512

typedef __attribute__((ext_vector_type(8))) short bfrag;  // 8 x bf16 (4 VGPRs)
typedef __attribute__((ext_vector_type(4))) float facc;   // MFMA f32 accum

#define AS1 __attribute__((address_space(1)))
#define AS3 __attribute__((address_space(3)))

__device__ __forceinline__ ushort f2bf(float x){
  union { float f; uint32_t u; } v; v.f = x;
  return (ushort)((v.u + 0x7fffu + ((v.u >> 16) & 1u)) >> 16);
}
__device__ __forceinline__ float bf2f(ushort x){
  union { uint32_t u; float f; } v; v.u = ((uint32_t)x) << 16; return v.f;
}
__device__ __forceinline__ uint32_t cvt_pk_bf16(float a, float b){
  uint32_t r;
  asm("v_cvt_pk_bf16_f32 %0, %1, %2" : "=v"(r) : "v"(a), "v"(b));
  return r;   // lo16 = bf16(a), hi16 = bf16(b), RNE
}

// ---- fp32 -> bf16 bulk convert (X) ----
__global__ void k_convert(const float* __restrict__ in, ushort* __restrict__ out){
  const size_t i = ((size_t)blockIdx.x * 256 + threadIdx.x) * 4;
  const float4 v = *(const float4*)(in + i);
  ushort4 o;
  o.x = f2bf(v.x); o.y = f2bf(v.y); o.z = f2bf(v.z); o.w = f2bf(v.w);
  *(ushort4*)(out + i) = o;
}

// ---- transpose-convert: in (2048 x N) f32 row-major -> out bf16 rows (rowoff+n), ld 2048 ----
__global__ void k_transpose(const float* __restrict__ in, ushort* __restrict__ out,
                            int N, int rowoff){
  __shared__ float t[32][33];
  const int k0 = blockIdx.x * 32, n0 = blockIdx.y * 32;
  const int tx = threadIdx.x, ty = threadIdx.y; // 32 x 8
#pragma unroll
  for (int i = 0; i < 4; ++i)
    t[ty + i*8][tx] = in[(size_t)(k0 + ty + i*8) * N + n0 + tx];
  __syncthreads();
#pragma unroll
  for (int i = 0; i < 4; ++i)
    out[(size_t)(rowoff + n0 + ty + i*8) * 2048 + k0 + tx] = f2bf(t[tx][ty + i*8]);
}

// ---- RoPE cos/sin table + bias concat (merged) ----
__global__ void k_prep(const int* __restrict__ pos, float* __restrict__ cosb,
                       float* __restrict__ sinb, const float* __restrict__ bq,
                       const float* __restrict__ bk, const float* __restrict__ bv,
                       float* __restrict__ bqkv){
  const int s = blockIdx.x, j = threadIdx.x; // 64 threads
  const float p = (float)pos[s];
  const float fr = expf(-(float)j * (13.815510557964274f / 64.f)); // 1/theta^(j/64)
  const float t = p * fr;
  cosb[s*64 + j] = cosf(t);
  sinb[s*64 + j] = sinf(t);
  const int idx = s*64 + j;
  if (idx < 2560)
    bqkv[idx] = idx < 2048 ? bq[idx] : (idx < 2304 ? bk[idx-2048] : bv[idx-2304]);
}

// ---- 2-phase prefetch bf16 GEMM: C[M,N] = A[M,K] * Bt[N,K]^T (+bias) ----
// If vtout != nullptr, blocks with n0 >= 2304 (V columns of the QKV GEMM) write
// output TRANSPOSED into vt (b,kv,d,s) as packed ushort4 (replaces k_vt).
template<bool HAS_BIAS, bool OUT_BF16>
__global__ __launch_bounds__(256, 3) void k_gemm(const ushort* __restrict__ A,
                                                 const ushort* __restrict__ Bt,
                                                 const float* __restrict__ bias,
                                                 void* __restrict__ Cout,
                                                 ushort* __restrict__ vtout,
                                                 int N, int K){
  __shared__ ushort As[2][128*32];
  __shared__ ushort Bs[2][128*32];
  const int m0 = blockIdx.x * 128;
  const int n0 = blockIdx.y * 128;
  const int tid = threadIdx.x;
  const int wave = tid >> 6, lane = tid & 63;
  const int wm = wave >> 1, wn = wave & 1;
  const int lrow = lane >> 4, lcol = lane & 15;
  facc acc[4][4] = {};

  auto stage = [&](int t, int buf){
    const int k0 = t * 32;
#pragma unroll
    for (int i = 0; i < 2; ++i){
      const int chunk = wave*2 + i;            // 0..7
      const int slot  = chunk*64 + lane;       // 0..511
      const int row   = slot >> 2, col8 = (slot & 3) * 8;
      const ushort* ga = A  + (size_t)(m0 + row) * K + k0 + col8;
      const ushort* gb = Bt + (size_t)(n0 + row) * K + k0 + col8;
      __builtin_amdgcn_global_load_lds((const AS1 void*)ga,
          (AS3 void*)(&As[buf][chunk*512]), 16, 0, 0);
      __builtin_amdgcn_global_load_lds((const AS1 void*)gb,
          (AS3 void*)(&Bs[buf][chunk*512]), 16, 0, 0);
    }
  };

  stage(0, 0);
  __syncthreads();
  const int nT = K >> 5;
  for (int t = 0; t < nT; ++t){
    const int buf = t & 1;
    if (t + 1 < nT) stage(t + 1, buf ^ 1);   // prefetch next tile (other buffer)
    bfrag af[4], bf[4];
#pragma unroll
    for (int mi = 0; mi < 4; ++mi)
      af[mi] = *(const bfrag*)(&As[buf][(wm*64 + mi*16 + lcol)*32 + lrow*8]);
#pragma unroll
    for (int ni = 0; ni < 4; ++ni)
      bf[ni] = *(const bfrag*)(&Bs[buf][(wn*64 + ni*16 + lcol)*32 + lrow*8]);
#pragma unroll
    for (int mi = 0; mi < 4; ++mi)
#pragma unroll
      for (int ni = 0; ni < 4; ++ni)
        acc[mi][ni] = __builtin_amdgcn_mfma_f32_16x16x32_bf16(af[mi], bf[ni], acc[mi][ni], 0, 0, 0);
    __syncthreads();                         // drains prefetch loads + LDS reads
  }

  if (vtout != nullptr && n0 >= 2304){       // V columns -> vt (b,kv,d,s), transposed
#pragma unroll
    for (int mi = 0; mi < 4; ++mi){
#pragma unroll
      for (int ni = 0; ni < 4; ++ni){
        const int col = n0 + wn*64 + ni*16 + lcol;   // 2304..2559
        const float bsv = HAS_BIAS ? bias[col] : 0.f;
        const int cv = col - 2304;
        const int kv = cv >> 7, d = cv & 127;
        const int row0 = m0 + wm*64 + mi*16 + lrow*4;
        const int bb = row0 >> 11, s0 = row0 & 2047;
        ushort4 w;
        w.x = f2bf(acc[mi][ni][0] + bsv);
        w.y = f2bf(acc[mi][ni][1] + bsv);
        w.z = f2bf(acc[mi][ni][2] + bsv);
        w.w = f2bf(acc[mi][ni][3] + bsv);
        *(ushort4*)(vtout + ((size_t)((bb*NKVh + kv)*HDd + d))*Ssz + s0) = w;
      }
    }
    return;
  }
#pragma unroll
  for (int mi = 0; mi < 4; ++mi){
#pragma unroll
    for (int ni = 0; ni < 4; ++ni){
      const int col = n0 + wn*64 + ni*16 + lcol;
      const float bsv = HAS_BIAS ? bias[col] : 0.f;
#pragma unroll
      for (int r = 0; r < 4; ++r){
        const size_t row = (size_t)m0 + wm*64 + mi*16 + lrow*4 + r;
        const float v = acc[mi][ni][r] + bsv;
        if (OUT_BF16) ((ushort*)Cout)[row * N + col] = f2bf(v);
        else          ((float*) Cout)[row * N + col] = v;
      }
    }
  }
}

// ---- in-place RoPE on q (cols 0..2047) and k (cols 2048..2303) of qkv ----
__global__ void k_rope(ushort* __restrict__ qkv, const float* __restrict__ cosb,
                       const float* __restrict__ sinb){
  const int s = blockIdx.x, b = blockIdx.y;
  ushort* rp = qkv + ((size_t)(b*Ssz + s)) * NQKV;
  const float* cb = cosb + s*64;
  const float* sb = sinb + s*64;
  for (int i = threadIdx.x; i < 18*64; i += 256){  // 16 q-heads + 2 kv-heads
    const int hh = i >> 6, d = i & 63;
    ushort* p = rp + hh*128 + d;
    const float x1 = bf2f(p[0]), x2 = bf2f(p[64]);
    const float c = cb[d], sn = sb[d];
    p[0]  = f2bf(x1*c  - x2*sn);
    p[64] = f2bf(x1*sn + x2*c);
  }
}

// ---- causal GQA flash attention, round 16: split-KV (round 14) + K/V DOUBLE-BUFFER ----
// Block p owns (A=p, B=31-p). Group 0 (waves 0-3): tile B, kv 0..16. Group 1 (waves
// 4-7): tile A kv 0..p, then tile B kv 17..31-p, then 1 dead step. 17 steps/wave,
// deterministic flat finish (round-14 verified). NEW: per-group K/V double buffers
// (LDS 144KB -> 1 block/CU): DMA(i+1)->buf^1 issued BEFORE step(i), ONE barrier per
// iteration whose vmcnt(0) drain has a full step of compute slack (round-7 pattern).
// Layout: [0,64K) group0 {K0,K1,V0,V1}, [64K,128K) group1 same, [128K,144K) P.
// Merge buffer overlays group-1 K/V space (dead after loop).
__global__ __launch_bounds__(512, 4) void k_attn(const ushort* __restrict__ qkv,
                                                 const ushort* __restrict__ vt,
                                                 ushort* __restrict__ out){
  __shared__ __attribute__((aligned(16))) char lds[147456];
  const int p = blockIdx.x, h = blockIdx.y, b = blockIdx.z;
  const int qtA = p, qtB = 31 - p;                // p <= 15 -> qtB >= 16
  const int kvh = h >> 3;                         // rep = NH/NKV = 8
  const int tid = threadIdx.x, wave = tid >> 6, lane = tid & 63;
  const int grp = wave >> 2, w4 = wave & 3;
  const int lrow = lane >> 4, lcol = lane & 15;
  const int tid4 = w4*64 + lane;                  // 0..255 within the group
  char* gbase = lds + grp*65536;                  // this group's K/V region
  char* pw    = lds + 131072 + wave*2048;
  const int qloc = w4*16 + lcol;                  // lane's q row within its 64-row tile

  const ushort* kb = qkv + (size_t)b*Ssz*NQKV + Hsz + kvh*HDd;
  const ushort* vb = vt + ((size_t)(b*NKVh + kvh))*HDd*Ssz;

  bfrag qf[4];
  auto loadQ = [&](int qx){
    const ushort* qp = qkv + ((size_t)b*Ssz + qx*64 + w4*16 + lcol)*NQKV + h*HDd + lrow*8;
#pragma unroll
    for (int kk = 0; kk < 4; ++kk) qf[kk] = *(const bfrag*)(qp + kk*32);
  };

  facc acc[8] = {};
  float m = -1e30f, l = 0.f;               // per-lane softmax state (q = lcol, log2 domain)

  // K tile (64x256B) + V tile (128x128B) -> buffer `buf` of this group's LDS, DMA.
  // Source pre-swizzled: LDS slot (row,c) holds X[row][c ^ ((row&7)<<4)].
  auto issueKV = [&](int t, int buf){
    char* kd = gbase + buf*16384;
    char* vd = gbase + 32768 + buf*16384;
    const ushort* kt = kb + (size_t)t*64*NQKV;
#pragma unroll
    for (int i = 0; i < 4; ++i){
      const int g = i*256 + tid4;
      const int row = g >> 4, c = (g & 15) * 16;
      const char* src = (const char*)(kt + (size_t)row*NQKV) + (c ^ ((row & 7) << 4));
      __builtin_amdgcn_global_load_lds((const AS1 void*)src,
          (AS3 void*)(kd + i*4096 + w4*1024), 16, 0, 0);
    }
#pragma unroll
    for (int i = 0; i < 4; ++i){
      const int g = i*256 + tid4;
      const int d = g >> 3, c = (g & 7) * 16;
      const char* src = (const char*)(vb + (size_t)d*Ssz + t*64) + (c ^ ((d & 7) << 4));
      __builtin_amdgcn_global_load_lds((const AS1 void*)src,
          (AS3 void*)(vd + i*4096 + w4*1024), 16, 0, 0);
    }
  };

  auto step = [&](int t, int qx, bool dead, int buf){
    const char* klds = gbase + buf*16384;
    const char* vlds = gbase + 32768 + buf*16384;
    facc sc[4] = {};
#pragma unroll
    for (int kk = 0; kk < 4; ++kk){        // S^T = K·Q^T: 16 MFMA, swizzled K reads
#pragma unroll
      for (int nt = 0; nt < 4; ++nt){
        const bfrag kf = *(const bfrag*)(klds + (nt*16 + lcol)*256 +
                                         ((kk*64 + lrow*16) ^ ((lcol & 7) << 4)));
        sc[nt] = __builtin_amdgcn_mfma_f32_16x16x32_bf16(kf, qf[kk], sc[nt], 0, 0, 0);
      }
    }
    const bool diag = (t == qx);
    float tm = -1e30f;
#pragma unroll
    for (int nt = 0; nt < 4; ++nt){        // scale+mask in place, running max
#pragma unroll
      for (int r = 0; r < 4; ++r){
        float sv = sc[nt][r] * 0.12752585778442352f;   // log2(e)/sqrt(128)
        if ((diag && (nt*16 + lrow*4 + r) > qloc) || dead) sv = -1e30f;
        sc[nt][r] = sv;
        tm = fmaxf(tm, sv);
      }
    }
    tm = fmaxf(tm, __shfl_xor(tm, 16));    // reduce over the 4 k-groups
    tm = fmaxf(tm, __shfl_xor(tm, 32));
    float mn = m, corr = 1.f;
    if (!__all(tm <= m + 11.5f)){          // defer-max: skip rescale when bounded
      mn = fmaxf(m, tm);
      corr = exp2f(m - mn);
#pragma unroll
      for (int r = 0; r < 4; ++r){
        const float ct = __shfl(corr, lrow*4 + r);
#pragma unroll
        for (int dt = 0; dt < 8; ++dt) acc[dt][r] *= ct;
      }
      m = mn;
    }
    float rs = 0.f;
#pragma unroll
    for (int nt = 0; nt < 4; ++nt){        // exp, sum, cvt_pk pack, P -> LDS 8B
      const float e0 = exp2f(sc[nt][0] - mn);
      const float e1 = exp2f(sc[nt][1] - mn);
      const float e2 = exp2f(sc[nt][2] - mn);
      const float e3 = exp2f(sc[nt][3] - mn);
      rs += (e0 + e1) + (e2 + e3);
      uint2 w;
      w.x = cvt_pk_bf16(e0, e1);
      w.y = cvt_pk_bf16(e2, e3);
      *(uint2*)(pw + lcol*128 + ((nt*32 + lrow*8) ^ ((lcol & 7) << 4))) = w;
    }
    rs += __shfl_xor(rs, 16);
    rs += __shfl_xor(rs, 32);
    l = l*corr + rs;
    asm volatile("s_waitcnt lgkmcnt(0)" ::: "memory");
#pragma unroll
    for (int kk2 = 0; kk2 < 2; ++kk2){     // PV: 16 MFMA, swizzled P/V reads
      const bfrag pa = *(const bfrag*)(pw + lcol*128 +
                                       ((kk2*64 + lrow*16) ^ ((lcol & 7) << 4)));
#pragma unroll
      for (int dt = 0; dt < 8; ++dt){
        const int vrow = dt*16 + lcol;
        const bfrag vf = *(const bfrag*)(vlds + vrow*128 +
                                         ((kk2*64 + lrow*16) ^ ((vrow & 7) << 4)));
        acc[dt] = __builtin_amdgcn_mfma_f32_16x16x32_bf16(pa, vf, acc[dt], 0, 0, 0);
      }
    }
  };

  auto writeOut = [&](int qx){             // normalize + store this wave's 16 rows
    float lt[4];
#pragma unroll
    for (int r = 0; r < 4; ++r) lt[r] = __shfl(l, lrow*4 + r);
#pragma unroll
    for (int r = 0; r < 4; ++r){
      const float inv = 1.f / lt[r];
      ushort* op = out + ((size_t)b*Ssz + qx*64 + w4*16 + lrow*4 + r)*Hsz + h*HDd;
#pragma unroll
      for (int dt = 0; dt < 8; dt += 2){
        const uint32_t u = cvt_pk_bf16(acc[dt][r] * inv, acc[dt+1][r] * inv);
        op[dt*16 + lcol]     = (ushort)(u & 0xffffu);
        op[(dt+1)*16 + lcol] = (ushort)(u >> 16);
      }
    }
  };

  int qx = grp ? qtA : qtB;
  loadQ(qx);
  issueKV(0, 0);
  __syncthreads();                         // drain tile-0 DMA

  int cur = 0;
  for (int i = 0; i <= 16; ++i){
    const int ni = i + 1;
    if (ni <= 16 && !((grp == 1) && (ni == 16))){   // prefetch next (skip dead)
      const int nkv = grp ? (ni <= p ? ni : 16 + ni - p) : ni;
      issueKV(nkv, cur ^ 1);
    }
    const int kv   = grp ? (i <= p ? i : 16 + i - p) : i;
    const bool dead = (grp == 1) && (i == 16);
    step(kv, qx, dead, cur);
    __syncthreads();                       // reads done + DMA(i+1) drained (full
    if (grp && i == p){                    //  step of compute slack before this)
      writeOut(qtA);
#pragma unroll
      for (int dt = 0; dt < 8; ++dt) acc[dt] = (facc){0.f, 0.f, 0.f, 0.f};
      m = -1e30f; l = 0.f;
      qx = qtB;
      loadQ(qtB);
    }
    cur ^= 1;
  }

  // merge tile B partials: group 1 -> LDS (overlays dead group-1 K/V), group 0 combines
  char* mb = lds + 65536 + w4*9216 + lane*144;   // 144B/lane: 8 x float4 acc + m + l
  if (grp){
#pragma unroll
    for (int dt = 0; dt < 8; ++dt) *(facc*)(mb + dt*16) = acc[dt];
    *(float*)(mb + 128) = m;
    *(float*)(mb + 132) = l;
  }
  __syncthreads();
  if (!grp){
    const float m1 = *(const float*)(mb + 128);
    const float l1 = *(const float*)(mb + 132);
    const float mf = fmaxf(m, m1);
    const float w0 = exp2f(m - mf), w1 = exp2f(m1 - mf);
    const float lf = l*w0 + l1*w1;
    facc a1[8];
#pragma unroll
    for (int dt = 0; dt < 8; ++dt) a1[dt] = *(const facc*)(mb + dt*16);
    float W0[4], W1[4], LI[4];
#pragma unroll
    for (int r = 0; r < 4; ++r){
      W0[r] = __shfl(w0, lrow*4 + r);
      W1[r] = __shfl(w1, lrow*4 + r);
      LI[r] = 1.f / __shfl(lf, lrow*4 + r);
    }
#pragma unroll
    for (int r = 0; r < 4; ++r){
      ushort* op = out + ((size_t)b*Ssz + qtB*64 + w4*16 + lrow*4 + r)*Hsz + h*HDd;
#pragma unroll
      for (int dt = 0; dt < 8; dt += 2){
        const float f0 = (acc[dt][r]  *W0[r] + a1[dt][r]  *W1[r]) * LI[r];
        const float f1 = (acc[dt+1][r]*W0[r] + a1[dt+1][r]*W1[r]) * LI[r];
        const uint32_t u = cvt_pk_bf16(f0, f1);
        op[dt*16 + lcol]     = (ushort)(u & 0xffffu);
        op[(dt+1)*16 + lcol] = (ushort)(u >> 16);
      }
    }
  }
}

extern "C" void kernel_launch(void* const* d_in, const int* in_sizes, int n_in,
                              void* d_out, int out_size, void* d_ws, size_t ws_size,
                              hipStream_t stream){
  (void)in_sizes; (void)n_in; (void)out_size;
  const float* hs  = (const float*)d_in[0];
  // d_in[1] = attention_mask: exactly causal 0/-1e9, applied analytically in k_attn
  const int*   pos = (const int*)  d_in[2];
  const float* Wq  = (const float*)d_in[3];
  const float* bq  = (const float*)d_in[4];
  const float* Wk  = (const float*)d_in[5];
  const float* bk  = (const float*)d_in[6];
  const float* Wv  = (const float*)d_in[7];
  const float* bv  = (const float*)d_in[8];
  const float* Wo  = (const float*)d_in[9];

  if (ws_size < 59779072) return;  // need ~57 MB scratch

  char* ws = (char*)d_ws;
  ushort* Xbf   = (ushort*)(ws + 0);          // 16,777,216 B; reused as attn output
  ushort* WqkvT = (ushort*)(ws + 16777216);   // 10,485,760 B (2560 x 2048 bf16)
  ushort* WoT   = (ushort*)(ws + 27262976);   //  8,388,608 B
  float*  bqkv  = (float*) (ws + 35651584);   //     10,240 B
  float*  cosb  = (float*) (ws + 35661824);   //    524,288 B
  float*  sinb  = (float*) (ws + 36186112);   //    524,288 B
  ushort* qkv   = (ushort*)(ws + 36710400);   // 20,971,520 B (4096 x 2560 bf16)
  ushort* vt    = (ushort*)(ws + 57681920);   //  2,097,152 B
  ushort* attn  = Xbf;

  k_convert  <<<8192, 256, 0, stream>>>(hs, Xbf);
  k_transpose<<<dim3(64,64), dim3(32,8), 0, stream>>>(Wq, WqkvT, 2048, 0);
  k_transpose<<<dim3(64, 8), dim3(32,8), 0, stream>>>(Wk, WqkvT, 256, 2048);
  k_transpose<<<dim3(64, 8), dim3(32,8), 0, stream>>>(Wv, WqkvT, 256, 2304);
  k_transpose<<<dim3(64,64), dim3(32,8), 0, stream>>>(Wo, WoT, 2048, 0);
  k_prep     <<<2048, 64, 0, stream>>>(pos, cosb, sinb, bq, bk, bv, bqkv);
  k_gemm<true,  true ><<<dim3(32,20), 256, 0, stream>>>(Xbf, WqkvT, bqkv, qkv, vt, 2560, 2048);
  k_rope     <<<dim3(2048,2), 256, 0, stream>>>(qkv, cosb, sinb);
  k_attn     <<<dim3(16,16,2), 512, 0, stream>>>(qkv, vt, attn);
  k_gemm<false, false><<<dim3(32,16), 256, 0, stream>>>(attn, WoT, nullptr, d_out, nullptr, 2048, 2048);
}

// Round 17
// 202.993 us; speedup vs baseline: 1.2467x; 1.1120x over previous
//
#include <hip/hip_runtime.h>
#include <stdint.h>

// Problem constants (B,S,H)=(2,2048,2048), NH=16, NKV=2, HD=128, theta=1e6
#define Bsz  2
#define Ssz  2048
#define Hsz  2048
#define NHh  16
#define NKVh 2
#define HDd  128
#define NQKV 2560   // H + 2*KV = 2048 + 512

typedef __attribute__((ext_vector_type(8))) short bfrag;  // 8 x bf16 (4 VGPRs)
typedef __attribute__((ext_vector_type(4))) float facc;   // MFMA f32 accum

#define AS1 __attribute__((address_space(1)))
#define AS3 __attribute__((address_space(3)))

__device__ __forceinline__ ushort f2bf(float x){
  union { float f; uint32_t u; } v; v.f = x;
  return (ushort)((v.u + 0x7fffu + ((v.u >> 16) & 1u)) >> 16);
}
__device__ __forceinline__ float bf2f(ushort x){
  union { uint32_t u; float f; } v; v.u = ((uint32_t)x) << 16; return v.f;
}
__device__ __forceinline__ uint32_t cvt_pk_bf16(float a, float b){
  uint32_t r;
  asm("v_cvt_pk_bf16_f32 %0, %1, %2" : "=v"(r) : "v"(a), "v"(b));
  return r;   // lo16 = bf16(a), hi16 = bf16(b), RNE
}

// ---- fp32 -> bf16 bulk convert (X) ----
__global__ void k_convert(const float* __restrict__ in, ushort* __restrict__ out){
  const size_t i = ((size_t)blockIdx.x * 256 + threadIdx.x) * 4;
  const float4 v = *(const float4*)(in + i);
  ushort4 o;
  o.x = f2bf(v.x); o.y = f2bf(v.y); o.z = f2bf(v.z); o.w = f2bf(v.w);
  *(ushort4*)(out + i) = o;
}

// ---- transpose-convert: in (2048 x N) f32 row-major -> out bf16 rows (rowoff+n), ld 2048 ----
__global__ void k_transpose(const float* __restrict__ in, ushort* __restrict__ out,
                            int N, int rowoff){
  __shared__ float t[32][33];
  const int k0 = blockIdx.x * 32, n0 = blockIdx.y * 32;
  const int tx = threadIdx.x, ty = threadIdx.y; // 32 x 8
#pragma unroll
  for (int i = 0; i < 4; ++i)
    t[ty + i*8][tx] = in[(size_t)(k0 + ty + i*8) * N + n0 + tx];
  __syncthreads();
#pragma unroll
  for (int i = 0; i < 4; ++i)
    out[(size_t)(rowoff + n0 + ty + i*8) * 2048 + k0 + tx] = f2bf(t[tx][ty + i*8]);
}

// ---- RoPE cos/sin table + bias concat (merged) ----
__global__ void k_prep(const int* __restrict__ pos, float* __restrict__ cosb,
                       float* __restrict__ sinb, const float* __restrict__ bq,
                       const float* __restrict__ bk, const float* __restrict__ bv,
                       float* __restrict__ bqkv){
  const int s = blockIdx.x, j = threadIdx.x; // 64 threads
  const float p = (float)pos[s];
  const float fr = expf(-(float)j * (13.815510557964274f / 64.f)); // 1/theta^(j/64)
  const float t = p * fr;
  cosb[s*64 + j] = cosf(t);
  sinb[s*64 + j] = sinf(t);
  const int idx = s*64 + j;
  if (idx < 2560)
    bqkv[idx] = idx < 2048 ? bq[idx] : (idx < 2304 ? bk[idx-2048] : bv[idx-2304]);
}

// ---- 2-phase prefetch bf16 GEMM: C[M,N] = A[M,K] * Bt[N,K]^T (+bias) ----
// QKV GEMM (vtout != nullptr): every 128-wide n-tile is exactly one head.
//   n0 >= 2304 : V head  -> output written TRANSPOSED into vt (b,kv,d,s).
//   n0 <  2304 : q/k head -> RoPE applied IN the epilogue (fp32, pre-rounding):
//     pair (d, d+64) spans the wn=0/wn=1 wave halves; wn=1 deposits acc+bias into
//     the dead staging LDS, wn=0 reads it and stores both rotated halves.
template<bool HAS_BIAS, bool OUT_BF16>
__global__ __launch_bounds__(256, 3) void k_gemm(const ushort* __restrict__ A,
                                                 const ushort* __restrict__ Bt,
                                                 const float* __restrict__ bias,
                                                 void* __restrict__ Cout,
                                                 ushort* __restrict__ vtout,
                                                 const float* __restrict__ cosb,
                                                 const float* __restrict__ sinb,
                                                 int N, int K){
  __shared__ __attribute__((aligned(16))) char smem[32768];
  ushort* As = (ushort*)smem;             // [2][128*32]
  ushort* Bs = (ushort*)(smem + 16384);   // [2][128*32]
  const int m0 = blockIdx.x * 128;
  const int n0 = blockIdx.y * 128;
  const int tid = threadIdx.x;
  const int wave = tid >> 6, lane = tid & 63;
  const int wm = wave >> 1, wn = wave & 1;
  const int lrow = lane >> 4, lcol = lane & 15;
  facc acc[4][4] = {};

  auto stage = [&](int t, int buf){
    const int k0 = t * 32;
#pragma unroll
    for (int i = 0; i < 2; ++i){
      const int chunk = wave*2 + i;            // 0..7
      const int slot  = chunk*64 + lane;       // 0..511
      const int row   = slot >> 2, col8 = (slot & 3) * 8;
      const ushort* ga = A  + (size_t)(m0 + row) * K + k0 + col8;
      const ushort* gb = Bt + (size_t)(n0 + row) * K + k0 + col8;
      __builtin_amdgcn_global_load_lds((const AS1 void*)ga,
          (AS3 void*)(As + buf*4096 + chunk*512), 16, 0, 0);
      __builtin_amdgcn_global_load_lds((const AS1 void*)gb,
          (AS3 void*)(Bs + buf*4096 + chunk*512), 16, 0, 0);
    }
  };

  stage(0, 0);
  __syncthreads();
  const int nT = K >> 5;
  for (int t = 0; t < nT; ++t){
    const int buf = t & 1;
    if (t + 1 < nT) stage(t + 1, buf ^ 1);   // prefetch next tile (other buffer)
    bfrag af[4], bf[4];
#pragma unroll
    for (int mi = 0; mi < 4; ++mi)
      af[mi] = *(const bfrag*)(As + buf*4096 + (wm*64 + mi*16 + lcol)*32 + lrow*8);
#pragma unroll
    for (int ni = 0; ni < 4; ++ni)
      bf[ni] = *(const bfrag*)(Bs + buf*4096 + (wn*64 + ni*16 + lcol)*32 + lrow*8);
#pragma unroll
    for (int mi = 0; mi < 4; ++mi)
#pragma unroll
      for (int ni = 0; ni < 4; ++ni)
        acc[mi][ni] = __builtin_amdgcn_mfma_f32_16x16x32_bf16(af[mi], bf[ni], acc[mi][ni], 0, 0, 0);
    __syncthreads();                         // drains prefetch loads + LDS reads
  }

  if (vtout != nullptr && n0 >= 2304){       // V head -> vt (b,kv,d,s), transposed
#pragma unroll
    for (int mi = 0; mi < 4; ++mi){
#pragma unroll
      for (int ni = 0; ni < 4; ++ni){
        const int col = n0 + wn*64 + ni*16 + lcol;   // 2304..2559
        const float bsv = HAS_BIAS ? bias[col] : 0.f;
        const int cv = col - 2304;
        const int kv = cv >> 7, d = cv & 127;
        const int row0 = m0 + wm*64 + mi*16 + lrow*4;
        const int bb = row0 >> 11, s0 = row0 & 2047;
        ushort4 w;
        w.x = f2bf(acc[mi][ni][0] + bsv);
        w.y = f2bf(acc[mi][ni][1] + bsv);
        w.z = f2bf(acc[mi][ni][2] + bsv);
        w.w = f2bf(acc[mi][ni][3] + bsv);
        *(ushort4*)(vtout + ((size_t)((bb*NKVh + kv)*HDd + d))*Ssz + s0) = w;
      }
    }
    return;
  }

  if (vtout != nullptr){                     // q/k head -> fused RoPE epilogue
    float* exch = (float*)smem;              // 2(wm) x 64row x 64col fp32 = 32KB
    if (wn == 1){                            // deposit x2 = acc + bias (cols d>=64)
#pragma unroll
      for (int mi = 0; mi < 4; ++mi)
#pragma unroll
        for (int ni = 0; ni < 4; ++ni){
          const float bsv = bias[n0 + 64 + ni*16 + lcol];
#pragma unroll
          for (int r = 0; r < 4; ++r)
            exch[wm*4096 + (mi*16 + lrow*4 + r)*64 + ni*16 + lcol] = acc[mi][ni][r] + bsv;
        }
    }
    __syncthreads();
    if (wn == 0){                            // rotate in fp32, store both halves
#pragma unroll
      for (int mi = 0; mi < 4; ++mi){
#pragma unroll
        for (int r = 0; r < 4; ++r){
          const int rl = mi*16 + lrow*4 + r;
          const size_t row = (size_t)m0 + wm*64 + rl;
          const int s = (int)(row & 2047);
#pragma unroll
          for (int ni = 0; ni < 4; ++ni){
            const int dl = ni*16 + lcol;     // 0..63
            const float c  = cosb[s*64 + dl];
            const float sn = sinb[s*64 + dl];
            const float x1 = acc[mi][ni][r] + bias[n0 + dl];
            const float x2 = exch[wm*4096 + rl*64 + dl];
            ((ushort*)Cout)[row*N + n0 + dl]      = f2bf(x1*c  - x2*sn);
            ((ushort*)Cout)[row*N + n0 + 64 + dl] = f2bf(x1*sn + x2*c);
          }
        }
      }
    }
    return;
  }

#pragma unroll
  for (int mi = 0; mi < 4; ++mi){
#pragma unroll
    for (int ni = 0; ni < 4; ++ni){
      const int col = n0 + wn*64 + ni*16 + lcol;
      const float bsv = HAS_BIAS ? bias[col] : 0.f;
#pragma unroll
      for (int r = 0; r < 4; ++r){
        const size_t row = (size_t)m0 + wm*64 + mi*16 + lrow*4 + r;
        const float v = acc[mi][ni][r] + bsv;
        if (OUT_BF16) ((ushort*)Cout)[row * N + col] = f2bf(v);
        else          ((float*) Cout)[row * N + col] = v;
      }
    }
  }
}

// ---- causal GQA flash attention (round-14 verified, FROZEN): split-KV groups ----
// Block p owns (A=p, B=31-p). Group 0 (waves 0-3): tile B, kv 0..16 (17 steps).
// Group 1 (waves 4-7): tile A kv 0..p, then tile B kv 17..31-p, then 1 dead step =
// 17 steps. Every wave active every iteration; LDS 80KB -> 2 blocks/CU; flat finish.
// Private K/V LDS per group via global_load_lds (zero staging VGPRs), source
// pre-swizzled. Tile B partials merge flash-style through LDS at the end.
__global__ __launch_bounds__(512, 4) void k_attn(const ushort* __restrict__ qkv,
                                                 const ushort* __restrict__ vt,
                                                 ushort* __restrict__ out){
  // [0,16K) K_g0 | [16K,32K) V_g0 | [32K,48K) K_g1 | [48K,64K) V_g1 | [64K,80K) P
  __shared__ __attribute__((aligned(16))) char lds[81920];
  const int p = blockIdx.x, h = blockIdx.y, b = blockIdx.z;
  const int qtA = p, qtB = 31 - p;                // p <= 15 -> qtB >= 16
  const int kvh = h >> 3;                         // rep = NH/NKV = 8
  const int tid = threadIdx.x, wave = tid >> 6, lane = tid & 63;
  const int grp = wave >> 2, w4 = wave & 3;
  const int lrow = lane >> 4, lcol = lane & 15;
  const int tid4 = w4*64 + lane;                  // 0..255 within the group
  char* klds = lds + grp*32768;
  char* vlds = klds + 16384;
  char* pw   = lds + 65536 + wave*2048;
  const int qloc = w4*16 + lcol;                  // lane's q row within its 64-row tile

  const ushort* kb = qkv + (size_t)b*Ssz*NQKV + Hsz + kvh*HDd;
  const ushort* vb = vt + ((size_t)(b*NKVh + kvh))*HDd*Ssz;

  bfrag qf[4];
  auto loadQ = [&](int qx){
    const ushort* qp = qkv + ((size_t)b*Ssz + qx*64 + w4*16 + lcol)*NQKV + h*HDd + lrow*8;
#pragma unroll
    for (int kk = 0; kk < 4; ++kk) qf[kk] = *(const bfrag*)(qp + kk*32);
  };

  facc acc[8] = {};
  float m = -1e30f, l = 0.f;               // per-lane softmax state (q = lcol, log2 domain)

  // K tile (64x256B) + V tile (128x128B) -> this group's LDS via DMA, 4 waves.
  // Source pre-swizzled: LDS slot (row,c) holds X[row][c ^ ((row&7)<<4)].
  auto issueKV = [&](int t){
    const ushort* kt = kb + (size_t)t*64*NQKV;
#pragma unroll
    for (int i = 0; i < 4; ++i){
      const int g = i*256 + tid4;
      const int row = g >> 4, c = (g & 15) * 16;
      const char* src = (const char*)(kt + (size_t)row*NQKV) + (c ^ ((row & 7) << 4));
      __builtin_amdgcn_global_load_lds((const AS1 void*)src,
          (AS3 void*)(klds + i*4096 + w4*1024), 16, 0, 0);
    }
#pragma unroll
    for (int i = 0; i < 4; ++i){
      const int g = i*256 + tid4;
      const int d = g >> 3, c = (g & 7) * 16;
      const char* src = (const char*)(vb + (size_t)d*Ssz + t*64) + (c ^ ((d & 7) << 4));
      __builtin_amdgcn_global_load_lds((const AS1 void*)src,
          (AS3 void*)(vlds + i*4096 + w4*1024), 16, 0, 0);
    }
  };

  auto step = [&](int t, int qx, bool dead){
    facc sc[4] = {};
#pragma unroll
    for (int kk = 0; kk < 4; ++kk){        // S^T = K·Q^T: 16 MFMA, swizzled K reads
#pragma unroll
      for (int nt = 0; nt < 4; ++nt){
        const bfrag kf = *(const bfrag*)(klds + (nt*16 + lcol)*256 +
                                         ((kk*64 + lrow*16) ^ ((lcol & 7) << 4)));
        sc[nt] = __builtin_amdgcn_mfma_f32_16x16x32_bf16(kf, qf[kk], sc[nt], 0, 0, 0);
      }
    }
    const bool diag = (t == qx);
    float tm = -1e30f;
#pragma unroll
    for (int nt = 0; nt < 4; ++nt){        // scale+mask in place, running max
#pragma unroll
      for (int r = 0; r < 4; ++r){
        float sv = sc[nt][r] * 0.12752585778442352f;   // log2(e)/sqrt(128)
        if ((diag && (nt*16 + lrow*4 + r) > qloc) || dead) sv = -1e30f;
        sc[nt][r] = sv;
        tm = fmaxf(tm, sv);
      }
    }
    tm = fmaxf(tm, __shfl_xor(tm, 16));    // reduce over the 4 k-groups
    tm = fmaxf(tm, __shfl_xor(tm, 32));
    float mn = m, corr = 1.f;
    if (!__all(tm <= m + 11.5f)){          // defer-max: skip rescale when bounded
      mn = fmaxf(m, tm);
      corr = exp2f(m - mn);
#pragma unroll
      for (int r = 0; r < 4; ++r){
        const float ct = __shfl(corr, lrow*4 + r);
#pragma unroll
        for (int dt = 0; dt < 8; ++dt) acc[dt][r] *= ct;
      }
      m = mn;
    }
    float rs = 0.f;
#pragma unroll
    for (int nt = 0; nt < 4; ++nt){        // exp, sum, cvt_pk pack, P -> LDS 8B
      const float e0 = exp2f(sc[nt][0] - mn);
      const float e1 = exp2f(sc[nt][1] - mn);
      const float e2 = exp2f(sc[nt][2] - mn);
      const float e3 = exp2f(sc[nt][3] - mn);
      rs += (e0 + e1) + (e2 + e3);
      uint2 w;
      w.x = cvt_pk_bf16(e0, e1);
      w.y = cvt_pk_bf16(e2, e3);
      *(uint2*)(pw + lcol*128 + ((nt*32 + lrow*8) ^ ((lcol & 7) << 4))) = w;
    }
    rs += __shfl_xor(rs, 16);
    rs += __shfl_xor(rs, 32);
    l = l*corr + rs;
    asm volatile("s_waitcnt lgkmcnt(0)" ::: "memory");
#pragma unroll
    for (int kk2 = 0; kk2 < 2; ++kk2){     // PV: 16 MFMA, swizzled P/V reads
      const bfrag pa = *(const bfrag*)(pw + lcol*128 +
                                       ((kk2*64 + lrow*16) ^ ((lcol & 7) << 4)));
#pragma unroll
      for (int dt = 0; dt < 8; ++dt){
        const int vrow = dt*16 + lcol;
        const bfrag vf = *(const bfrag*)(vlds + vrow*128 +
                                         ((kk2*64 + lrow*16) ^ ((vrow & 7) << 4)));
        acc[dt] = __builtin_amdgcn_mfma_f32_16x16x32_bf16(pa, vf, acc[dt], 0, 0, 0);
      }
    }
  };

  auto writeOut = [&](int qx){             // normalize + store this wave's 16 rows
    float lt[4];
#pragma unroll
    for (int r = 0; r < 4; ++r) lt[r] = __shfl(l, lrow*4 + r);
#pragma unroll
    for (int r = 0; r < 4; ++r){
      const float inv = 1.f / lt[r];
      ushort* op = out + ((size_t)b*Ssz + qx*64 + w4*16 + lrow*4 + r)*Hsz + h*HDd;
#pragma unroll
      for (int dt = 0; dt < 8; dt += 2){
        const uint32_t u = cvt_pk_bf16(acc[dt][r] * inv, acc[dt+1][r] * inv);
        op[dt*16 + lcol]     = (ushort)(u & 0xffffu);
        op[(dt+1)*16 + lcol] = (ushort)(u >> 16);
      }
    }
  };

  int qx = grp ? qtA : qtB;
  loadQ(qx);
  issueKV(0);                              // both groups: kv 0 first
  __syncthreads();                         // implicit vmcnt(0) drain

  for (int i = 0; i <= 16; ++i){
    const int kv   = grp ? (i <= p ? i : 16 + i - p) : i;
    const bool dead = (grp == 1) && (i == 16);
    step(kv, qx, dead);
    __syncthreads();                       // all 8 waves done reading LDS
    if (grp && i == p){                    // tile A complete: write, reset, switch to B
      writeOut(qtA);
#pragma unroll
      for (int dt = 0; dt < 8; ++dt) acc[dt] = (facc){0.f, 0.f, 0.f, 0.f};
      m = -1e30f; l = 0.f;
      qx = qtB;
      loadQ(qtB);
    }
    if (i < 16){
      const int ni = i + 1;
      const int nkv = grp ? (ni <= p ? ni : 16 + ni - p) : ni;
      if (!((grp == 1) && (ni == 16))) issueKV(nkv);   // skip staging for dead step
      __syncthreads();                     // drains DMA; K/V(i+1) visible
    }
  }

  // merge tile B partials: group 1 -> LDS (overlays dead K_g1/V_g1/P[w0,w1]), group 0 combines
  char* mb = lds + 32768 + w4*9216 + lane*144;   // 144B/lane: 8 x float4 acc + m + l
  if (grp){
#pragma unroll
    for (int dt = 0; dt < 8; ++dt) *(facc*)(mb + dt*16) = acc[dt];
    *(float*)(mb + 128) = m;
    *(float*)(mb + 132) = l;
  }
  __syncthreads();
  if (!grp){
    const float m1 = *(const float*)(mb + 128);
    const float l1 = *(const float*)(mb + 132);
    const float mf = fmaxf(m, m1);
    const float w0 = exp2f(m - mf), w1 = exp2f(m1 - mf);
    const float lf = l*w0 + l1*w1;
    facc a1[8];
#pragma unroll
    for (int dt = 0; dt < 8; ++dt) a1[dt] = *(const facc*)(mb + dt*16);
    float W0[4], W1[4], LI[4];
#pragma unroll
    for (int r = 0; r < 4; ++r){
      W0[r] = __shfl(w0, lrow*4 + r);
      W1[r] = __shfl(w1, lrow*4 + r);
      LI[r] = 1.f / __shfl(lf, lrow*4 + r);
    }
#pragma unroll
    for (int r = 0; r < 4; ++r){
      ushort* op = out + ((size_t)b*Ssz + qtB*64 + w4*16 + lrow*4 + r)*Hsz + h*HDd;
#pragma unroll
      for (int dt = 0; dt < 8; dt += 2){
        const float f0 = (acc[dt][r]  *W0[r] + a1[dt][r]  *W1[r]) * LI[r];
        const float f1 = (acc[dt+1][r]*W0[r] + a1[dt+1][r]*W1[r]) * LI[r];
        const uint32_t u = cvt_pk_bf16(f0, f1);
        op[dt*16 + lcol]     = (ushort)(u & 0xffffu);
        op[(dt+1)*16 + lcol] = (ushort)(u >> 16);
      }
    }
  }
}

extern "C" void kernel_launch(void* const* d_in, const int* in_sizes, int n_in,
                              void* d_out, int out_size, void* d_ws, size_t ws_size,
                              hipStream_t stream){
  (void)in_sizes; (void)n_in; (void)out_size;
  const float* hs  = (const float*)d_in[0];
  // d_in[1] = attention_mask: exactly causal 0/-1e9, applied analytically in k_attn
  const int*   pos = (const int*)  d_in[2];
  const float* Wq  = (const float*)d_in[3];
  const float* bq  = (const float*)d_in[4];
  const float* Wk  = (const float*)d_in[5];
  const float* bk  = (const float*)d_in[6];
  const float* Wv  = (const float*)d_in[7];
  const float* bv  = (const float*)d_in[8];
  const float* Wo  = (const float*)d_in[9];

  if (ws_size < 59779072) return;  // need ~57 MB scratch

  char* ws = (char*)d_ws;
  ushort* Xbf   = (ushort*)(ws + 0);          // 16,777,216 B; reused as attn output
  ushort* WqkvT = (ushort*)(ws + 16777216);   // 10,485,760 B (2560 x 2048 bf16)
  ushort* WoT   = (ushort*)(ws + 27262976);   //  8,388,608 B
  float*  bqkv  = (float*) (ws + 35651584);   //     10,240 B
  float*  cosb  = (float*) (ws + 35661824);   //    524,288 B
  float*  sinb  = (float*) (ws + 36186112);   //    524,288 B
  ushort* qkv   = (ushort*)(ws + 36710400);   // 20,971,520 B (4096 x 2560 bf16)
  ushort* vt    = (ushort*)(ws + 57681920);   //  2,097,152 B
  ushort* attn  = Xbf;

  k_convert  <<<8192, 256, 0, stream>>>(hs, Xbf);
  k_transpose<<<dim3(64,64), dim3(32,8), 0, stream>>>(Wq, WqkvT, 2048, 0);
  k_transpose<<<dim3(64, 8), dim3(32,8), 0, stream>>>(Wk, WqkvT, 256, 2048);
  k_transpose<<<dim3(64, 8), dim3(32,8), 0, stream>>>(Wv, WqkvT, 256, 2304);
  k_transpose<<<dim3(64,64), dim3(32,8), 0, stream>>>(Wo, WoT, 2048, 0);
  k_prep     <<<2048, 64, 0, stream>>>(pos, cosb, sinb, bq, bk, bv, bqkv);
  k_gemm<true,  true ><<<dim3(32,20), 256, 0, stream>>>(Xbf, WqkvT, bqkv, qkv, vt,
                                                        cosb, sinb, 2560, 2048);
  k_attn     <<<dim3(16,16,2), 512, 0, stream>>>(qkv, vt, attn);
  k_gemm<false, false><<<dim3(32,16), 256, 0, stream>>>(attn, WoT, nullptr, d_out,
                                                        nullptr, nullptr, nullptr, 2048, 2048);
}